// Round 3
// baseline (14820.428 us; speedup 1.0000x reference)
//
#include <hip/hip_runtime.h>
#include <hip/hip_bf16.h>

#define BATCH 32
#define SEQ   512
#define IND   1024
#define HD    1024
#define ZD    2048   // IN + H
#define NG    4096   // 4*H
#define WG_ELEMS (1024 * 2048)   // elements per gate weight matrix

typedef short  shortx8 __attribute__((ext_vector_type(8)));
typedef float  floatx4 __attribute__((ext_vector_type(4)));

#define MFMA16(a, b, c) __builtin_amdgcn_mfma_f32_16x16x32_bf16((a), (b), (c), 0, 0, 0)

__device__ __forceinline__ float sigmoidf_(float x) {
    return 1.0f / (1.0f + __expf(-x));
}
__device__ __forceinline__ float tanhf_(float x) {
    return 1.0f - 2.0f / (__expf(2.0f * x) + 1.0f);
}

__device__ __forceinline__ short bf16s(float x) {
    __hip_bfloat16 h = __float2bfloat16(x);
    return *reinterpret_cast<short*>(&h);
}

// load 8 consecutive fp32, round to bf16, pack into an MFMA fragment half
__device__ __forceinline__ shortx8 cvt8(const float* __restrict__ p) {
    float4 v0 = *(const float4*)p;
    float4 v1 = *(const float4*)(p + 4);
    shortx8 r;
    r[0] = bf16s(v0.x); r[1] = bf16s(v0.y); r[2] = bf16s(v0.z); r[3] = bf16s(v0.w);
    r[4] = bf16s(v1.x); r[5] = bf16s(v1.y); r[6] = bf16s(v1.z); r[7] = bf16s(v1.w);
    return r;
}

// ---------------------------------------------------------------------------
// fp32 -> bf16 weight conversion (one-time per launch). n % 4 == 0.
// ---------------------------------------------------------------------------
__global__ __launch_bounds__(256) void cvt_f32_bf16(
    const float* __restrict__ src, __hip_bfloat16* __restrict__ dst, int n)
{
    int i = (blockIdx.x * 256 + threadIdx.x) * 4;
    if (i < n) {
        float4 v = *(const float4*)(src + i);
        dst[i + 0] = __float2bfloat16(v.x);
        dst[i + 1] = __float2bfloat16(v.y);
        dst[i + 2] = __float2bfloat16(v.z);
        dst[i + 3] = __float2bfloat16(v.w);
    }
}

// ---------------------------------------------------------------------------
// Kernel 1: x-part gate pre-activations for a chunk of T time steps.
// Gx[(t-t0)*B + b][g*1024+j] = sum_k x[b][t][k] * Wg[j][1024+k] + bias_g[j]
// A read from fp32 x (cvt on the fly), B from pre-converted bf16 weights.
// M = T*B rows (t-major), K = 1024, N = 4096. Wave tile 64x64 (4x4 MFMA).
// grid = T*8 blocks of 256.
// ---------------------------------------------------------------------------
__global__ __launch_bounds__(256) void gemm_gx(
    const float* __restrict__ x,
    const __hip_bfloat16* __restrict__ Wb,     // [4][1024][2048] bf16
    const float* __restrict__ bf_, const float* __restrict__ bi_,
    const float* __restrict__ bc_, const float* __restrict__ bo_,
    __hip_bfloat16* __restrict__ Gx, const int t0)
{
    const int wave = (blockIdx.x << 2) + (threadIdx.x >> 6);
    const int mt = wave >> 6;   // chunk-row tile
    const int nt = wave & 63;   // gate-col tile
    const int lane = threadIdx.x & 63;
    const int quad = lane >> 4;
    const int l16  = lane & 15;
    const int m0 = mt << 6;
    const int n0 = nt << 6;
    const int g  = n0 >> 10;                 // gate index, uniform per tile
    const __hip_bfloat16* Wg = Wb + (size_t)g * WG_ELEMS;
    const float* bg = (g == 0) ? bf_ : (g == 1) ? bi_ : (g == 2) ? bc_ : bo_;
    const int j0 = n0 & 1023;

    floatx4 acc[4][4];
#pragma unroll
    for (int i = 0; i < 4; i++)
#pragma unroll
        for (int j = 0; j < 4; j++) acc[i][j] = (floatx4)(0.0f);

    const float* arow[4];
    const __hip_bfloat16* brow[4];
#pragma unroll
    for (int i = 0; i < 4; i++) {
        const int r = m0 + i * 16 + l16;        // chunk-local row, t-major
        const int t = t0 + (r >> 5);
        const int b = r & 31;
        arow[i] = x + ((size_t)b * SEQ + t) * IND + quad * 8;
    }
#pragma unroll
    for (int j = 0; j < 4; j++)
        brow[j] = Wg + (size_t)(j0 + j * 16 + l16) * ZD + HD + quad * 8;

    for (int k0 = 0; k0 < IND; k0 += 32) {
        shortx8 a[4], b[4];
#pragma unroll
        for (int i = 0; i < 4; i++) a[i] = cvt8(arow[i] + k0);
#pragma unroll
        for (int j = 0; j < 4; j++) b[j] = *(const shortx8*)(brow[j] + k0);
#pragma unroll
        for (int i = 0; i < 4; i++)
#pragma unroll
            for (int j = 0; j < 4; j++)
                acc[i][j] = MFMA16(a[i], b[j], acc[i][j]);
    }

#pragma unroll
    for (int j = 0; j < 4; j++) {
        const int n  = n0 + j * 16 + l16;      // gate column (0..4095)
        const int jj = j0 + j * 16 + l16;      // within-gate column
        const float bias = bg[jj];
#pragma unroll
        for (int i = 0; i < 4; i++) {
#pragma unroll
            for (int r = 0; r < 4; r++) {
                const int row = m0 + i * 16 + quad * 4 + r;   // chunk-local, t-major
                Gx[(size_t)row * NG + n] = __float2bfloat16(acc[i][j][r] + bias);
            }
        }
    }
}

// ---------------------------------------------------------------------------
// Kernel 2: one LSTM time step.
// Gh[b][g*1024+j] = sum_k h_in[b][k] * Wg[j][k]   (M=32, K=1024)
// Each wave owns 16 j-columns x all 4 gates -> pointwise update is wave-local.
// h double-buffered across launches. grid = 16 blocks of 256.
// ---------------------------------------------------------------------------
__global__ __launch_bounds__(256) void lstm_step(
    const __hip_bfloat16* __restrict__ gx,     // [B][NG] for this t (bias included)
    const int t,
    const __hip_bfloat16* __restrict__ Wb,     // [4][1024][2048] bf16
    const __hip_bfloat16* __restrict__ h_in,   // [B][H] bf16
    __hip_bfloat16* __restrict__ h_out,        // [B][H] bf16
    float* __restrict__ c,                     // [B][H] fp32
    __hip_bfloat16* __restrict__ hs)           // [B][S][H] bf16
{
    const int jt = (blockIdx.x << 2) + (threadIdx.x >> 6); // 0..63
    const int lane = threadIdx.x & 63;
    const int quad = lane >> 4;
    const int l16  = lane & 15;
    const int j0   = jt << 4;

    const __hip_bfloat16* wrow[4];
#pragma unroll
    for (int g = 0; g < 4; g++)
        wrow[g] = Wb + (size_t)g * WG_ELEMS + (size_t)(j0 + l16) * ZD + quad * 8;

    const __hip_bfloat16* hrow0 = h_in + (size_t)l16 * HD + quad * 8;
    const __hip_bfloat16* hrow1 = h_in + (size_t)(16 + l16) * HD + quad * 8;

    floatx4 acc[4][2];
#pragma unroll
    for (int g = 0; g < 4; g++) { acc[g][0] = (floatx4)(0.0f); acc[g][1] = (floatx4)(0.0f); }

    for (int k0 = 0; k0 < HD; k0 += 32) {
        shortx8 a0 = *(const shortx8*)(hrow0 + k0);
        shortx8 a1 = *(const shortx8*)(hrow1 + k0);
#pragma unroll
        for (int g = 0; g < 4; g++) {
            shortx8 bfrag = *(const shortx8*)(wrow[g] + k0);
            acc[g][0] = MFMA16(a0, bfrag, acc[g][0]);
            acc[g][1] = MFMA16(a1, bfrag, acc[g][1]);
        }
    }

    const int j = j0 + l16;
#pragma unroll
    for (int i = 0; i < 2; i++) {
#pragma unroll
        for (int r = 0; r < 4; r++) {
            const int bb = i * 16 + quad * 4 + r;
            const size_t gbase = (size_t)bb * NG + j;
            const float fp = acc[0][i][r] + __bfloat162float(gx[gbase + 0 * HD]);
            const float ip = acc[1][i][r] + __bfloat162float(gx[gbase + 1 * HD]);
            const float cp = acc[2][i][r] + __bfloat162float(gx[gbase + 2 * HD]);
            const float op = acc[3][i][r] + __bfloat162float(gx[gbase + 3 * HD]);
            const float fg = sigmoidf_(fp);
            const float ig = sigmoidf_(ip);
            const float cg = tanhf_(cp);
            const float og = sigmoidf_(op);
            const size_t ci = (size_t)bb * HD + j;
            const float cnew = ig * cg + fg * c[ci];
            const float hnew = og * tanhf_(cnew);
            c[ci] = cnew;
            const __hip_bfloat16 hb = __float2bfloat16(hnew);
            h_out[ci] = hb;
            hs[((size_t)bb * SEQ + t) * HD + j] = hb;
        }
    }
}

// ---------------------------------------------------------------------------
// Kernel 3: out[r][n] = sum_k hs[r][k] * Wfc[n][k] + bfc[n]   (fp32 out)
// M = 16384 (r = b*512+s), K = 1024, N = 1024. Wave tile 64x64.
// grid = 1024 blocks of 256.
// ---------------------------------------------------------------------------
__global__ __launch_bounds__(256) void gemm_fc(
    const __hip_bfloat16* __restrict__ hs,
    const __hip_bfloat16* __restrict__ Wfcb,   // [1024][1024] bf16
    const float* __restrict__ bfc,
    float* __restrict__ out)
{
    const int wave = (blockIdx.x << 2) + (threadIdx.x >> 6);
    const int mt = wave >> 4;   // 0..255
    const int nt = wave & 15;   // 0..15
    const int lane = threadIdx.x & 63;
    const int quad = lane >> 4;
    const int l16  = lane & 15;
    const int m0 = mt << 6;
    const int n0 = nt << 6;

    floatx4 acc[4][4];
#pragma unroll
    for (int i = 0; i < 4; i++)
#pragma unroll
        for (int j = 0; j < 4; j++) acc[i][j] = (floatx4)(0.0f);

    const __hip_bfloat16* arow[4];
    const __hip_bfloat16* brow[4];
#pragma unroll
    for (int i = 0; i < 4; i++)
        arow[i] = hs + (size_t)(m0 + i * 16 + l16) * HD + quad * 8;
#pragma unroll
    for (int j = 0; j < 4; j++)
        brow[j] = Wfcb + (size_t)(n0 + j * 16 + l16) * HD + quad * 8;

    for (int k0 = 0; k0 < HD; k0 += 32) {
        shortx8 a[4], b[4];
#pragma unroll
        for (int i = 0; i < 4; i++) a[i] = *(const shortx8*)(arow[i] + k0);
#pragma unroll
        for (int j = 0; j < 4; j++) b[j] = *(const shortx8*)(brow[j] + k0);
#pragma unroll
        for (int i = 0; i < 4; i++)
#pragma unroll
            for (int j = 0; j < 4; j++)
                acc[i][j] = MFMA16(a[i], b[j], acc[i][j]);
    }

#pragma unroll
    for (int j = 0; j < 4; j++) {
        const int n = n0 + j * 16 + l16;
        const float bias = bfc[n];
#pragma unroll
        for (int i = 0; i < 4; i++) {
#pragma unroll
            for (int r = 0; r < 4; r++) {
                const int row = m0 + i * 16 + quad * 4 + r;
                out[(size_t)row * 1024 + n] = acc[i][j][r] + bias;
            }
        }
    }
}

// ---------------------------------------------------------------------------
extern "C" void kernel_launch(void* const* d_in, const int* in_sizes, int n_in,
                              void* d_out, int out_size, void* d_ws, size_t ws_size,
                              hipStream_t stream) {
    const float* x   = (const float*)d_in[0];
    const float* Wf  = (const float*)d_in[1];
    const float* bf_ = (const float*)d_in[2];
    const float* Wi  = (const float*)d_in[3];
    const float* bi_ = (const float*)d_in[4];
    const float* Wc  = (const float*)d_in[5];
    const float* bc_ = (const float*)d_in[6];
    const float* Wo  = (const float*)d_in[7];
    const float* bo_ = (const float*)d_in[8];
    const float* Wfc = (const float*)d_in[9];
    const float* bfc = (const float*)d_in[10];
    float* out = (float*)d_out;

    // ---- ws layout (bytes) ----
    // [0)            4x gate weights bf16  : 16 MiB
    // [16M)          Wfc bf16              :  2 MiB
    // [18M)          hs  bf16 [B][S][H]    : 32 MiB
    // [50M)          h0,h1 bf16 + c fp32   : 256 KiB
    // [50.25M)       Gx bf16 chunk         : T_CHUNK * 256 KiB
    char* ws = (char*)d_ws;
    const size_t WB_OFF  = 0;
    const size_t WFC_OFF = (size_t)4 * WG_ELEMS * 2;                  // 16,777,216
    const size_t HS_OFF  = WFC_OFF + (size_t)HD * HD * 2;             // 18,874,368
    const size_t ST_OFF  = HS_OFF + (size_t)BATCH * SEQ * HD * 2;     // 52,428,800
    const size_t ST_BYTES = (size_t)BATCH * HD * 2 * 2 + (size_t)BATCH * HD * 4; // 262,144
    const size_t GX_OFF  = ST_OFF + ST_BYTES;                         // 52,690,944

    __hip_bfloat16* Wb   = (__hip_bfloat16*)(ws + WB_OFF);
    __hip_bfloat16* Wfcb = (__hip_bfloat16*)(ws + WFC_OFF);
    __hip_bfloat16* hs   = (__hip_bfloat16*)(ws + HS_OFF);
    __hip_bfloat16* h0   = (__hip_bfloat16*)(ws + ST_OFF);
    __hip_bfloat16* h1   = h0 + (size_t)BATCH * HD;
    float*          c    = (float*)(ws + ST_OFF + 2 * (size_t)BATCH * HD * 2);
    __hip_bfloat16* Gx   = (__hip_bfloat16*)(ws + GX_OFF);

    // pick largest time chunk that fits ws (deterministic -> graph-safe)
    int T_CHUNK = 1;
    {
        const int opts[6] = {512, 128, 32, 8, 2, 1};
        for (int i = 0; i < 6; i++) {
            const size_t need = GX_OFF + (size_t)opts[i] * BATCH * NG * 2;
            if (need <= ws_size) { T_CHUNK = opts[i]; break; }
        }
    }

    // one-time weight conversion fp32 -> bf16
    cvt_f32_bf16<<<2048, 256, 0, stream>>>(Wf, Wb + 0 * (size_t)WG_ELEMS, WG_ELEMS);
    cvt_f32_bf16<<<2048, 256, 0, stream>>>(Wi, Wb + 1 * (size_t)WG_ELEMS, WG_ELEMS);
    cvt_f32_bf16<<<2048, 256, 0, stream>>>(Wc, Wb + 2 * (size_t)WG_ELEMS, WG_ELEMS);
    cvt_f32_bf16<<<2048, 256, 0, stream>>>(Wo, Wb + 3 * (size_t)WG_ELEMS, WG_ELEMS);
    cvt_f32_bf16<<<1024, 256, 0, stream>>>(Wfc, Wfcb, HD * HD);

    // zero h0 + h1 + c (ws is poisoned 0xAA before every launch)
    hipMemsetAsync(ws + ST_OFF, 0, ST_BYTES, stream);

    for (int t0 = 0; t0 < SEQ; t0 += T_CHUNK) {
        gemm_gx<<<T_CHUNK * 8, 256, 0, stream>>>(
            x, Wb, bf_, bi_, bc_, bo_, Gx, t0);
        for (int t = t0; t < t0 + T_CHUNK; t++) {
            const __hip_bfloat16* gx_t = Gx + (size_t)(t - t0) * BATCH * NG;
            const __hip_bfloat16* hin  = (t & 1) ? h1 : h0;
            __hip_bfloat16*       hout = (t & 1) ? h0 : h1;
            lstm_step<<<16, 256, 0, stream>>>(gx_t, t, Wb, hin, hout, c, hs);
        }
    }

    gemm_fc<<<1024, 256, 0, stream>>>(hs, Wfcb, bfc, out);
}